// Round 11
// baseline (165.320 us; speedup 1.0000x reference)
//
#include <hip/hip_runtime.h>

typedef __bf16 bf16x8 __attribute__((ext_vector_type(8)));
typedef __bf16 bf16x4 __attribute__((ext_vector_type(4)));
typedef float  f32x4  __attribute__((ext_vector_type(4)));

#define NPIX  3136      // 56*56 = 49*64 (no tails)
#define WIMG  56
#define CCH   128
#define NH    4
#define HD    32
#define NSPLIT 8        // key-splits per (head, 64q) tile
// 32^-0.5 * log2(e): q pre-scaled so softmax uses exp2 directly
#define QSCALE 0.2550565470841439f

#if __has_builtin(__builtin_amdgcn_exp2f)
#define FEXP2(x) __builtin_amdgcn_exp2f(x)
#else
#define FEXP2(x) __expf((x) * 0.6931471805599453f)
#endif

// MFMA 16x16x32 maps (HW-verified R1-R10):
//   A[m=lane&15][k=(lane>>4)*8+j]   B[k=(lane>>4)*8+j][n=lane&15]
//   D: col(n)=lane&15, row(m)=(lane>>4)*4+reg
// Transpose-free attention (R8-R10): S^T = MFMA(A=K-frag, B=Q-frag) with the
// pi key-slot permutation baked into kT/vP makes exp(S^T) regs the PV B-frags.
// R11 = R10 kernels EXACTLY, each launched TWICE (idempotent) to decompose
// dur_us into kernel-time vs fixed per-iteration overhead:
//   kernels+gaps = dur_R11 - dur_R10;  F = 2*dur_R10 - dur_R11.

__device__ __forceinline__ int perm_inv(int k) {
    return (((k >> 5) & 1) * 2 + ((k >> 2) & 1)) * 16 + (((k >> 3) & 3) * 4) + (k & 3);
}

// ---------------------------------------------------------------------------
// K1: qkv = qkv_w @ x + qkv_b, bf16 MFMA (M=384, K=128, N=6272).  (R10 kernel)
// ---------------------------------------------------------------------------
__global__ __launch_bounds__(256) void k_qkv(
    const float* __restrict__ x, const float* __restrict__ qkv_w,
    const float* __restrict__ qkv_b,
    __bf16* __restrict__ qT, __bf16* __restrict__ kT,
    __bf16* __restrict__ vT, __bf16* __restrict__ vP)
{
    __shared__ __bf16 xl[64][136];                 // [px][c], row stride 272B
    const int tid = threadIdx.x;
    const int w = tid >> 6, lane = tid & 63;
    const int col = lane & 15, g = lane >> 4;
    const int px0 = blockIdx.x * 64;
    const int slab = blockIdx.y;                   // 0 q, 1 k, 2 v
    const int b = blockIdx.z;
    const int obase = slab * 128 + w * 32;

    {   // stage x tile (coalesced dword loads, packed b64 LDS writes)
        const int px = tid & 63, cq = tid >> 6;
        const float* xp = x + (size_t)b * CCH * NPIX + px0 + px;
        #pragma unroll
        for (int i = 0; i < 8; ++i) {
            const int c0 = cq * 4 + i * 16;
            const float v0 = xp[(size_t)(c0 + 0) * NPIX];
            const float v1 = xp[(size_t)(c0 + 1) * NPIX];
            const float v2 = xp[(size_t)(c0 + 2) * NPIX];
            const float v3 = xp[(size_t)(c0 + 3) * NPIX];
            bf16x4 bv = {(__bf16)v0, (__bf16)v1, (__bf16)v2, (__bf16)v3};
            *(bf16x4*)&xl[px][c0] = bv;
        }
    }
    __syncthreads();

    f32x4 acc[2][4];                               // [out tile][px tile]
    #pragma unroll
    for (int ot = 0; ot < 2; ++ot)
        #pragma unroll
        for (int a = 0; a < 4; ++a) acc[ot][a] = (f32x4){0.f, 0.f, 0.f, 0.f};

    #pragma unroll
    for (int ks = 0; ks < 4; ++ks) {
        const int c0 = ks * 32 + g * 8;
        #pragma unroll
        for (int ot = 0; ot < 2; ++ot) {
            const float* wrow = qkv_w + (size_t)(obase + ot * 16 + col) * CCH + c0;
            const float4 wA = *(const float4*)(wrow);
            const float4 wB = *(const float4*)(wrow + 4);
            bf16x8 af = {(__bf16)wA.x, (__bf16)wA.y, (__bf16)wA.z, (__bf16)wA.w,
                         (__bf16)wB.x, (__bf16)wB.y, (__bf16)wB.z, (__bf16)wB.w};
            #pragma unroll
            for (int a = 0; a < 4; ++a) {
                const bf16x8 bf_ = *(const bf16x8*)&xl[16 * a + col][c0];  // one b128
                acc[ot][a] = __builtin_amdgcn_mfma_f32_16x16x32_bf16(af, bf_, acc[ot][a], 0, 0, 0);
            }
        }
    }

    #pragma unroll
    for (int ot = 0; ot < 2; ++ot) {
        const int orow = obase + ot * 16 + g * 4;      // global output row
        const f32x4 bias4 = *(const f32x4*)(qkv_b + orow);
        if (slab == 0) {                               // ---- q (scaled) ----
            const int o = orow, h = o >> 5, d0 = o & 31;
            __bf16* dst = qT + ((size_t)(b * NH + h) * NPIX) * HD + d0;
            #pragma unroll
            for (int a = 0; a < 4; ++a) {
                const int px = px0 + 16 * a + col;
                bf16x4 v;
                #pragma unroll
                for (int r = 0; r < 4; ++r) v[r] = (__bf16)((acc[ot][a][r] + bias4[r]) * QSCALE);
                *(bf16x4*)(dst + (size_t)px * HD) = v;
            }
        } else if (slab == 1) {                        // ---- k (pi-permuted rows) ----
            const int o = orow - 128, h = o >> 5, d0 = o & 31;
            __bf16* dst = kT + ((size_t)(b * NH + h) * NPIX) * HD + d0;
            #pragma unroll
            for (int a = 0; a < 4; ++a) {
                const int s = perm_inv(16 * a + col);  // slot for key kappa
                bf16x4 v;
                #pragma unroll
                for (int r = 0; r < 4; ++r) v[r] = (__bf16)(acc[ot][a][r] + bias4[r]);
                *(bf16x4*)(dst + (size_t)(px0 + s) * HD) = v;
            }
        } else {                                       // ---- v: vT + pi-permuted vP ----
            const int c = orow - 256;
            #pragma unroll
            for (int a = 0; a < 4; ++a) {
                const int px = px0 + 16 * a + col;
                const int s = perm_inv(16 * a + col);
                bf16x4 v;
                #pragma unroll
                for (int r = 0; r < 4; ++r) v[r] = (__bf16)(acc[ot][a][r] + bias4[r]);
                *(bf16x4*)(vT + ((size_t)(b * NPIX + px)) * CCH + c) = v;
                #pragma unroll
                for (int r = 0; r < 4; ++r)
                    vP[((size_t)(b * CCH + c + r)) * NPIX + px0 + s] = v[r];
            }
        }
    }
}

// ---------------------------------------------------------------------------
// K2: attention partials, LDS-shared chunk stream, transpose-free. (R10 kernel)
// grid (13, 8, 8), block 256 = 4 waves = 4 adjacent 64-q tiles, one split.
// ---------------------------------------------------------------------------
__global__ __launch_bounds__(256) void k_attn(
    const __bf16* __restrict__ qT, const __bf16* __restrict__ kT,
    const __bf16* __restrict__ vP,
    __bf16* __restrict__ pO, float* __restrict__ pl)
{
    __shared__ __bf16 Kl[2][64][32];       // [buf][slot][d] -- source layout
    __shared__ __bf16 Vl[2][32][72];       // [buf][d][slot], +8 pad

    const int tid = threadIdx.x;
    const int w = tid >> 6, lane = tid & 63;
    const int col = lane & 15, g = lane >> 4;
    const int qt = blockIdx.x * 4 + w;          // 0..51; 49..51 idle
    const bool valid = qt < 49;
    const int qtc = valid ? qt : 48;
    const int bh = blockIdx.y, sp = blockIdx.z;
    const int b = bh >> 2, h = bh & 3;
    const int qbase = qtc * 64;
    const size_t headoff = (size_t)bh * NPIX * HD;
    const int c0h = h * HD;

    const __bf16* qbp = qT + headoff + (size_t)(qbase + col) * HD + g * 8;
    const bf16x8 aq0 = *(const bf16x8*)(qbp);
    const bf16x8 aq1 = *(const bf16x8*)(qbp + 16 * HD);
    const bf16x8 aq2 = *(const bf16x8*)(qbp + 32 * HD);
    const bf16x8 aq3 = *(const bf16x8*)(qbp + 48 * HD);

    const __bf16 one = (__bf16)1.0f;
    const bf16x8 ones = {one, one, one, one, one, one, one, one};

    f32x4 O00 = {0,0,0,0}, O01 = {0,0,0,0}, O10 = {0,0,0,0}, O11 = {0,0,0,0};
    f32x4 O20 = {0,0,0,0}, O21 = {0,0,0,0}, O30 = {0,0,0,0}, O31 = {0,0,0,0};
    f32x4 La0 = {0,0,0,0}, La1 = {0,0,0,0}, La2 = {0,0,0,0}, La3 = {0,0,0,0};

    const __bf16* kTh = kT + headoff;
    const int vr = tid >> 3;                    // 0..31 (d row)
    const int vo = (tid & 7) * 8;               // elem offset within chunk
    const __bf16* vsrc = vP + (size_t)(b * CCH + c0h + vr) * NPIX + vo;

    const int cs = (49 * sp) >> 3, ce = (49 * (sp + 1)) >> 3;   // 6 or 7 chunks

#define STAGE(BUF, CHUNK) do { const int _k0 = (CHUNK) * 64;                           \
        *(bf16x8*)(&Kl[BUF][0][0] + tid * 8) =                                         \
            *(const bf16x8*)(kTh + (size_t)_k0 * HD + tid * 8);                        \
        *(bf16x8*)(&Vl[BUF][vr][vo]) = *(const bf16x8*)(vsrc + _k0);                   \
    } while (0)

#define SQH(AQ, O0R, O1R, LAR)  do {                                                   \
        f32x4 s0 = __builtin_amdgcn_mfma_f32_16x16x32_bf16(ck0, AQ, zz, 0, 0, 0);      \
        f32x4 s1 = __builtin_amdgcn_mfma_f32_16x16x32_bf16(ck1, AQ, zz, 0, 0, 0);      \
        f32x4 s2 = __builtin_amdgcn_mfma_f32_16x16x32_bf16(ck2, AQ, zz, 0, 0, 0);      \
        f32x4 s3 = __builtin_amdgcn_mfma_f32_16x16x32_bf16(ck3, AQ, zz, 0, 0, 0);      \
        bf16x8 P0 = {(__bf16)FEXP2(s0[0]), (__bf16)FEXP2(s0[1]),                       \
                     (__bf16)FEXP2(s0[2]), (__bf16)FEXP2(s0[3]),                       \
                     (__bf16)FEXP2(s1[0]), (__bf16)FEXP2(s1[1]),                       \
                     (__bf16)FEXP2(s1[2]), (__bf16)FEXP2(s1[3])};                      \
        bf16x8 P1 = {(__bf16)FEXP2(s2[0]), (__bf16)FEXP2(s2[1]),                       \
                     (__bf16)FEXP2(s2[2]), (__bf16)FEXP2(s2[3]),                       \
                     (__bf16)FEXP2(s3[0]), (__bf16)FEXP2(s3[1]),                       \
                     (__bf16)FEXP2(s3[2]), (__bf16)FEXP2(s3[3])};                      \
        O0R = __builtin_amdgcn_mfma_f32_16x16x32_bf16(vv00, P0, O0R, 0, 0, 0);         \
        O0R = __builtin_amdgcn_mfma_f32_16x16x32_bf16(vv01, P1, O0R, 0, 0, 0);         \
        O1R = __builtin_amdgcn_mfma_f32_16x16x32_bf16(vv10, P0, O1R, 0, 0, 0);         \
        O1R = __builtin_amdgcn_mfma_f32_16x16x32_bf16(vv11, P1, O1R, 0, 0, 0);         \
        LAR = __builtin_amdgcn_mfma_f32_16x16x32_bf16(ones, P0, LAR, 0, 0, 0);         \
        LAR = __builtin_amdgcn_mfma_f32_16x16x32_bf16(ones, P1, LAR, 0, 0, 0);         \
    } while (0)

#define COMPUTE(CUR) do {                                                              \
        const __bf16* Kb = &Kl[CUR][0][0];                                             \
        const __bf16* Vb = &Vl[CUR][0][0];                                             \
        const bf16x8 ck0 = *(const bf16x8*)(Kb + (      col) * 32 + g * 8);            \
        const bf16x8 ck1 = *(const bf16x8*)(Kb + (16 + col) * 32 + g * 8);             \
        const bf16x8 ck2 = *(const bf16x8*)(Kb + (32 + col) * 32 + g * 8);             \
        const bf16x8 ck3 = *(const bf16x8*)(Kb + (48 + col) * 32 + g * 8);             \
        const bf16x8 vv00 = *(const bf16x8*)(Vb + (      col) * 72      + g * 8);      \
        const bf16x8 vv01 = *(const bf16x8*)(Vb + (      col) * 72 + 32 + g * 8);      \
        const bf16x8 vv10 = *(const bf16x8*)(Vb + (16 + col) * 72      + g * 8);       \
        const bf16x8 vv11 = *(const bf16x8*)(Vb + (16 + col) * 72 + 32 + g * 8);       \
        const f32x4 zz = {0.f, 0.f, 0.f, 0.f};                                         \
        SQH(aq0, O00, O01, La0);                                                       \
        SQH(aq1, O10, O11, La1);                                                       \
        SQH(aq2, O20, O21, La2);                                                       \
        SQH(aq3, O30, O31, La3);                                                       \
    } while (0)

    STAGE(0, cs);
    __syncthreads();
    for (int cc = cs; cc < ce; ++cc) {
        const int cur = (cc - cs) & 1;
        if (cc + 1 < ce) STAGE(cur ^ 1, cc + 1);   // overlaps with compute(cur)
        COMPUTE(cur);
        __syncthreads();                           // staging done + cur consumed
    }
#undef STAGE
#undef SQH
#undef COMPUTE

    if (!valid) return;
    const int t = bh * 49 + qt;
    __bf16* po = pO + ((size_t)t * NSPLIT + sp) * 64 * 32;
    float* plp = pl + ((size_t)t * NSPLIT + sp) * 64;
#define STQH(QH, O0R, O1R, LAR) do {                                                   \
        bf16x4 v0 = {(__bf16)O0R[0], (__bf16)O0R[1], (__bf16)O0R[2], (__bf16)O0R[3]};  \
        bf16x4 v1 = {(__bf16)O1R[0], (__bf16)O1R[1], (__bf16)O1R[2], (__bf16)O1R[3]};  \
        *(bf16x4*)(po + ((QH) * 16 + col) * 32      + g * 4) = v0;                     \
        *(bf16x4*)(po + ((QH) * 16 + col) * 32 + 16 + g * 4) = v1;                     \
        if (g == 0) plp[(QH) * 16 + col] = LAR[0];                                     \
    } while (0)
    STQH(0, O00, O01, La0);
    STQH(1, O10, O11, La1);
    STQH(2, O20, O21, La2);
    STQH(3, O30, O31, La3);
#undef STQH
}

// ---------------------------------------------------------------------------
// K3: reduce 8 split partials + normalize + LePE + bias -> attnT.  (R10 kernel)
// ---------------------------------------------------------------------------
__global__ __launch_bounds__(256) void k_reduce(
    const __bf16* __restrict__ pO, const float* __restrict__ pl,
    const __bf16* __restrict__ vT,
    const float* __restrict__ lepe_w, const float* __restrict__ lepe_b,
    __bf16* __restrict__ attnT)
{
    __shared__ float wl[32][25];
    __shared__ float bl[32];
    const int tid = threadIdx.x;
    const int qt = blockIdx.x, bh = blockIdx.y;
    const int b = bh >> 2, h = bh & 3;
    const int c0h = h * HD;

    for (int i = tid; i < 800; i += 256) ((float*)wl)[i] = lepe_w[c0h * 25 + i];
    if (tid < 32) bl[tid] = lepe_b[c0h + tid];
    __syncthreads();

    const int q  = tid >> 2;                   // 0..63
    const int dg = (tid & 3) * 8;              // 0,8,16,24
    const size_t t = (size_t)bh * 49 + qt;

    float lt = 0.f;
    float o[8] = {0.f, 0.f, 0.f, 0.f, 0.f, 0.f, 0.f, 0.f};
    #pragma unroll
    for (int s = 0; s < NSPLIT; ++s) {
        lt += pl[(t * NSPLIT + s) * 64 + q];
        const bf16x8 pv = *(const bf16x8*)(pO + ((t * NSPLIT + s) * 64 + q) * 32 + dg);
        #pragma unroll
        for (int i = 0; i < 8; ++i) o[i] += (float)pv[i];
    }
    const float linv = 1.0f / lt;
    #pragma unroll
    for (int i = 0; i < 8; ++i) o[i] = o[i] * linv + bl[dg + i];

    const int px = qt * 64 + q;
    const int py = px / WIMG, pxx = px % WIMG;
    const __bf16* vtb = vT + ((size_t)b * NPIX) * CCH + c0h + dg;
    #pragma unroll
    for (int dy = 0; dy < 5; ++dy) {
        const int yy = py + dy - 2;
        if (yy < 0 || yy >= WIMG) continue;
        #pragma unroll
        for (int dx = 0; dx < 5; ++dx) {
            const int xx = pxx + dx - 2;
            if (xx < 0 || xx >= WIMG) continue;
            const bf16x8 vv = *(const bf16x8*)(vtb + (size_t)(yy * WIMG + xx) * CCH);
            const int tap = dy * 5 + dx;
            #pragma unroll
            for (int i = 0; i < 8; ++i) o[i] += (float)vv[i] * wl[dg + i][tap];
        }
    }
    bf16x8 ov = {(__bf16)o[0], (__bf16)o[1], (__bf16)o[2], (__bf16)o[3],
                 (__bf16)o[4], (__bf16)o[5], (__bf16)o[6], (__bf16)o[7]};
    *(bf16x8*)(attnT + ((size_t)(b * NPIX + px)) * CCH + c0h + dg) = ov;
}

// ---------------------------------------------------------------------------
// K4: out = proj_w @ (attn+lepe) + proj_b, bf16 MFMA, zero LDS.  (R10 kernel)
// ---------------------------------------------------------------------------
__global__ __launch_bounds__(256) void k_proj(
    const __bf16* __restrict__ attnT, const float* __restrict__ proj_w,
    const float* __restrict__ proj_b, float* __restrict__ out)
{
    const int tid = threadIdx.x;
    const int w = tid >> 6, lane = tid & 63;
    const int col = lane & 15, g = lane >> 4;
    const int px0 = blockIdx.x * 32 + (w >> 1) * 16;
    const int obase = blockIdx.y * 32 + (w & 1) * 16;
    const int b = blockIdx.z;

    const float* wrow = proj_w + (size_t)(obase + col) * CCH;
    const __bf16* abase = attnT + (size_t)(b * NPIX + px0) * CCH;

    f32x4 acc = {0.f, 0.f, 0.f, 0.f};
    #pragma unroll
    for (int ks = 0; ks < 4; ++ks) {
        const int c0 = ks * 32 + g * 8;
        const float4 wA = *(const float4*)(wrow + c0);
        const float4 wB = *(const float4*)(wrow + c0 + 4);
        bf16x8 af = {(__bf16)wA.x, (__bf16)wA.y, (__bf16)wA.z, (__bf16)wA.w,
                     (__bf16)wB.x, (__bf16)wB.y, (__bf16)wB.z, (__bf16)wB.w};
        const bf16x8 bf_ = *(const bf16x8*)(abase + (size_t)col * CCH + c0);
        acc = __builtin_amdgcn_mfma_f32_16x16x32_bf16(af, bf_, acc, 0, 0, 0);
    }

    const f32x4 pb = *(const f32x4*)(proj_b + obase + g * 4);
    #pragma unroll
    for (int r = 0; r < 4; ++r)
        out[(size_t)(b * CCH + obase + g * 4 + r) * NPIX + px0 + col] = acc[r] + pb[r];
}

// ---------------------------------------------------------------------------
// R11 instrumented launch: every kernel twice (idempotent -> identical output).
// dur_R11 - dur_R10 = true kernel+gap time; 2*dur_R10 - dur_R11 = fixed
// per-iteration overhead F that kernels cannot touch.
// ---------------------------------------------------------------------------
extern "C" void kernel_launch(void* const* d_in, const int* in_sizes, int n_in,
                              void* d_out, int out_size, void* d_ws, size_t ws_size,
                              hipStream_t stream)
{
    const float* x      = (const float*)d_in[0];
    const float* qkv_w  = (const float*)d_in[1];
    const float* qkv_b  = (const float*)d_in[2];
    const float* lepe_w = (const float*)d_in[3];
    const float* lepe_b = (const float*)d_in[4];
    const float* proj_w = (const float*)d_in[5];
    const float* proj_b = (const float*)d_in[6];
    float* out = (float*)d_out;

    char* p = (char*)d_ws;                                   // ~22 MB total
    __bf16* qT    = (__bf16*)p;  p += (size_t)2 * NH * NPIX * HD * 2;       // 1.6 MB
    __bf16* kT    = (__bf16*)p;  p += (size_t)2 * NH * NPIX * HD * 2;       // 1.6 MB
    __bf16* vT    = (__bf16*)p;  p += (size_t)2 * NPIX * CCH * 2;           // 1.6 MB
    __bf16* vP    = (__bf16*)p;  p += (size_t)2 * CCH * NPIX * 2;           // 1.6 MB
    __bf16* attnT = (__bf16*)p;  p += (size_t)2 * NPIX * CCH * 2;           // 1.6 MB
    __bf16* pO    = (__bf16*)p;  p += (size_t)392 * NSPLIT * 64 * 32 * 2;   // 12.8 MB
    float*  pl    = (float*)p;                                              // 0.8 MB

    k_qkv   <<<dim3(49, 3, 2), dim3(256), 0, stream>>>(x, qkv_w, qkv_b, qT, kT, vT, vP);
    k_qkv   <<<dim3(49, 3, 2), dim3(256), 0, stream>>>(x, qkv_w, qkv_b, qT, kT, vT, vP);
    k_attn  <<<dim3(13, 8, 8), dim3(256), 0, stream>>>(qT, kT, vP, pO, pl);
    k_attn  <<<dim3(13, 8, 8), dim3(256), 0, stream>>>(qT, kT, vP, pO, pl);
    k_reduce<<<dim3(49, 8),    dim3(256), 0, stream>>>(pO, pl, vT, lepe_w, lepe_b, attnT);
    k_reduce<<<dim3(49, 8),    dim3(256), 0, stream>>>(pO, pl, vT, lepe_w, lepe_b, attnT);
    k_proj  <<<dim3(98, 4, 2), dim3(256), 0, stream>>>(attnT, proj_w, proj_b, out);
    k_proj  <<<dim3(98, 4, 2), dim3(256), 0, stream>>>(attnT, proj_w, proj_b, out);
}

// Round 12
// 119.833 us; speedup vs baseline: 1.3796x; 1.3796x over previous
//
#include <hip/hip_runtime.h>

typedef __bf16 bf16x8 __attribute__((ext_vector_type(8)));
typedef __bf16 bf16x4 __attribute__((ext_vector_type(4)));
typedef float  f32x4  __attribute__((ext_vector_type(4)));

#define NPIX  3136      // 56*56 = 49*64 (no tails)
#define WIMG  56
#define CCH   128
#define NH    4
#define HD    32
#define NSPLIT 8        // key-splits per (head, 64q) tile
// 32^-0.5 * log2(e): q pre-scaled so softmax uses exp2 directly
#define QSCALE 0.2550565470841439f

#if __has_builtin(__builtin_amdgcn_exp2f)
#define FEXP2(x) __builtin_amdgcn_exp2f(x)
#else
#define FEXP2(x) __expf((x) * 0.6931471805599453f)
#endif

// MFMA 16x16x32 maps (HW-verified R1-R11):
//   A[m=lane&15][k=(lane>>4)*8+j]   B[k=(lane>>4)*8+j][n=lane&15]
//   D: col(n)=lane&15, row(m)=(lane>>4)*4+reg
// Transpose-free attention (R8-R11): S^T = MFMA(A=K-frag, B=Q-frag) with the
// pi key-slot permutation baked into kT/vP makes exp(S^T) regs the PV B-frags.
// pi operates on 64-key-aligned blocks and maps [0,32)->[0,32), [32,64)->[32,64).
// R11 calibration: fixed harness overhead F ~= 79 us; kernels+gaps ~= 43 us.
// R12: qkv 2x blocks (588); attn __launch_bounds__(256,4) + low-transient SQH
// to reach 4 waves/SIMD on the exp-bound VALU pipe.

__device__ __forceinline__ int perm_inv(int k) {
    return (((k >> 5) & 1) * 2 + ((k >> 2) & 1)) * 16 + (((k >> 3) & 3) * 4) + (k & 3);
}

// ---------------------------------------------------------------------------
// K1: qkv = qkv_w @ x + qkv_b, bf16 MFMA (M=384, K=128, N=6272).
// grid (98, 3, 2) = 588 blocks (2.3 waves/SIMD; was 294/1.15), block 256.
// px tile 32. kT rows / vP columns written pi-permuted (64-key-aligned base).
// ---------------------------------------------------------------------------
__global__ __launch_bounds__(256) void k_qkv(
    const float* __restrict__ x, const float* __restrict__ qkv_w,
    const float* __restrict__ qkv_b,
    __bf16* __restrict__ qT, __bf16* __restrict__ kT,
    __bf16* __restrict__ vT, __bf16* __restrict__ vP)
{
    __shared__ __bf16 xl[32][136];                 // [px][c], row stride 272B
    const int tid = threadIdx.x;
    const int w = tid >> 6, lane = tid & 63;
    const int col = lane & 15, g = lane >> 4;
    const int px0 = blockIdx.x * 32;
    const int slab = blockIdx.y;                   // 0 q, 1 k, 2 v
    const int b = blockIdx.z;
    const int obase = slab * 128 + w * 32;
    const int kbase = px0 & ~63;                   // pi 64-key block base
    const int khalf = px0 & 32;

    {   // stage x tile (coalesced 128B rows, packed b64 LDS writes)
        const int px = tid & 31, cq = tid >> 5;    // cq 0..7
        const float* xp = x + (size_t)b * CCH * NPIX + px0 + px;
        #pragma unroll
        for (int i = 0; i < 4; ++i) {
            const int c0 = cq * 4 + i * 32;
            const float v0 = xp[(size_t)(c0 + 0) * NPIX];
            const float v1 = xp[(size_t)(c0 + 1) * NPIX];
            const float v2 = xp[(size_t)(c0 + 2) * NPIX];
            const float v3 = xp[(size_t)(c0 + 3) * NPIX];
            bf16x4 bv = {(__bf16)v0, (__bf16)v1, (__bf16)v2, (__bf16)v3};
            *(bf16x4*)&xl[px][c0] = bv;
        }
    }
    __syncthreads();

    f32x4 acc[2][2];                               // [out tile][px tile]
    #pragma unroll
    for (int ot = 0; ot < 2; ++ot)
        #pragma unroll
        for (int a = 0; a < 2; ++a) acc[ot][a] = (f32x4){0.f, 0.f, 0.f, 0.f};

    #pragma unroll
    for (int ks = 0; ks < 4; ++ks) {
        const int c0 = ks * 32 + g * 8;
        #pragma unroll
        for (int ot = 0; ot < 2; ++ot) {
            const float* wrow = qkv_w + (size_t)(obase + ot * 16 + col) * CCH + c0;
            const float4 wA = *(const float4*)(wrow);
            const float4 wB = *(const float4*)(wrow + 4);
            bf16x8 af = {(__bf16)wA.x, (__bf16)wA.y, (__bf16)wA.z, (__bf16)wA.w,
                         (__bf16)wB.x, (__bf16)wB.y, (__bf16)wB.z, (__bf16)wB.w};
            #pragma unroll
            for (int a = 0; a < 2; ++a) {
                const bf16x8 bf_ = *(const bf16x8*)&xl[16 * a + col][c0];  // one b128
                acc[ot][a] = __builtin_amdgcn_mfma_f32_16x16x32_bf16(af, bf_, acc[ot][a], 0, 0, 0);
            }
        }
    }

    #pragma unroll
    for (int ot = 0; ot < 2; ++ot) {
        const int orow = obase + ot * 16 + g * 4;      // global output row
        const f32x4 bias4 = *(const f32x4*)(qkv_b + orow);
        if (slab == 0) {                               // ---- q (scaled) ----
            const int o = orow, h = o >> 5, d0 = o & 31;
            __bf16* dst = qT + ((size_t)(b * NH + h) * NPIX) * HD + d0;
            #pragma unroll
            for (int a = 0; a < 2; ++a) {
                const int px = px0 + 16 * a + col;
                bf16x4 v;
                #pragma unroll
                for (int r = 0; r < 4; ++r) v[r] = (__bf16)((acc[ot][a][r] + bias4[r]) * QSCALE);
                *(bf16x4*)(dst + (size_t)px * HD) = v;
            }
        } else if (slab == 1) {                        // ---- k (pi-permuted rows) ----
            const int o = orow - 128, h = o >> 5, d0 = o & 31;
            __bf16* dst = kT + ((size_t)(b * NH + h) * NPIX) * HD + d0;
            #pragma unroll
            for (int a = 0; a < 2; ++a) {
                const int s = perm_inv(khalf + 16 * a + col);  // slot for key kappa
                bf16x4 v;
                #pragma unroll
                for (int r = 0; r < 4; ++r) v[r] = (__bf16)(acc[ot][a][r] + bias4[r]);
                *(bf16x4*)(dst + (size_t)(kbase + s) * HD) = v;
            }
        } else {                                       // ---- v: vT + pi-permuted vP ----
            const int c = orow - 256;
            #pragma unroll
            for (int a = 0; a < 2; ++a) {
                const int px = px0 + 16 * a + col;
                const int s = perm_inv(khalf + 16 * a + col);
                bf16x4 v;
                #pragma unroll
                for (int r = 0; r < 4; ++r) v[r] = (__bf16)(acc[ot][a][r] + bias4[r]);
                *(bf16x4*)(vT + ((size_t)(b * NPIX + px)) * CCH + c) = v;
                #pragma unroll
                for (int r = 0; r < 4; ++r)
                    vP[((size_t)(b * CCH + c + r)) * NPIX + kbase + s] = v[r];
            }
        }
    }
}

// ---------------------------------------------------------------------------
// K2: attention partials, LDS-shared chunk stream, transpose-free.
// grid (13, 8, 8), block 256 = 4 waves = 4 adjacent 64-q tiles, one split.
// R12: __launch_bounds__(256,4) -> VGPR<=128 -> 4 blocks/CU (16 waves/CU);
// SQH restructured so s0/s1 retire into P0 before s2/s3 exist (peak regs
// ~124: 76 persistent + 48 transient). The kernel is exp-issue-bound
// (78.7M quarter-rate exps); TLP is the lever.
// ---------------------------------------------------------------------------
__global__ __launch_bounds__(256, 4) void k_attn(
    const __bf16* __restrict__ qT, const __bf16* __restrict__ kT,
    const __bf16* __restrict__ vP,
    __bf16* __restrict__ pO, float* __restrict__ pl)
{
    __shared__ __bf16 Kl[2][64][32];       // [buf][slot][d] -- source layout
    __shared__ __bf16 Vl[2][32][72];       // [buf][d][slot], +8 pad

    const int tid = threadIdx.x;
    const int w = tid >> 6, lane = tid & 63;
    const int col = lane & 15, g = lane >> 4;
    const int qt = blockIdx.x * 4 + w;          // 0..51; 49..51 idle
    const bool valid = qt < 49;
    const int qtc = valid ? qt : 48;
    const int bh = blockIdx.y, sp = blockIdx.z;
    const int b = bh >> 2, h = bh & 3;
    const int qbase = qtc * 64;
    const size_t headoff = (size_t)bh * NPIX * HD;
    const int c0h = h * HD;

    const __bf16* qbp = qT + headoff + (size_t)(qbase + col) * HD + g * 8;
    const bf16x8 aq0 = *(const bf16x8*)(qbp);
    const bf16x8 aq1 = *(const bf16x8*)(qbp + 16 * HD);
    const bf16x8 aq2 = *(const bf16x8*)(qbp + 32 * HD);
    const bf16x8 aq3 = *(const bf16x8*)(qbp + 48 * HD);

    const __bf16 one = (__bf16)1.0f;
    const bf16x8 ones = {one, one, one, one, one, one, one, one};

    f32x4 O00 = {0,0,0,0}, O01 = {0,0,0,0}, O10 = {0,0,0,0}, O11 = {0,0,0,0};
    f32x4 O20 = {0,0,0,0}, O21 = {0,0,0,0}, O30 = {0,0,0,0}, O31 = {0,0,0,0};
    f32x4 La0 = {0,0,0,0}, La1 = {0,0,0,0}, La2 = {0,0,0,0}, La3 = {0,0,0,0};

    const __bf16* kTh = kT + headoff;
    const int vr = tid >> 3;                    // 0..31 (d row)
    const int vo = (tid & 7) * 8;               // elem offset within chunk
    const __bf16* vsrc = vP + (size_t)(b * CCH + c0h + vr) * NPIX + vo;

    const int cs = (49 * sp) >> 3, ce = (49 * (sp + 1)) >> 3;   // 6 or 7 chunks

#define STAGE(BUF, CHUNK) do { const int _k0 = (CHUNK) * 64;                           \
        *(bf16x8*)(&Kl[BUF][0][0] + tid * 8) =                                         \
            *(const bf16x8*)(kTh + (size_t)_k0 * HD + tid * 8);                        \
        *(bf16x8*)(&Vl[BUF][vr][vo]) = *(const bf16x8*)(vsrc + _k0);                   \
    } while (0)

    // low-transient SQH: s0/s1 -> P0 retired before s2/s3 computed
#define SQH(AQ, O0R, O1R, LAR)  do {                                                   \
        f32x4 s0 = __builtin_amdgcn_mfma_f32_16x16x32_bf16(ck0, AQ, zz, 0, 0, 0);      \
        f32x4 s1 = __builtin_amdgcn_mfma_f32_16x16x32_bf16(ck1, AQ, zz, 0, 0, 0);      \
        bf16x8 P0 = {(__bf16)FEXP2(s0[0]), (__bf16)FEXP2(s0[1]),                       \
                     (__bf16)FEXP2(s0[2]), (__bf16)FEXP2(s0[3]),                       \
                     (__bf16)FEXP2(s1[0]), (__bf16)FEXP2(s1[1]),                       \
                     (__bf16)FEXP2(s1[2]), (__bf16)FEXP2(s1[3])};                      \
        O0R = __builtin_amdgcn_mfma_f32_16x16x32_bf16(vv00, P0, O0R, 0, 0, 0);         \
        O1R = __builtin_amdgcn_mfma_f32_16x16x32_bf16(vv10, P0, O1R, 0, 0, 0);         \
        LAR = __builtin_amdgcn_mfma_f32_16x16x32_bf16(ones, P0, LAR, 0, 0, 0);         \
        f32x4 s2 = __builtin_amdgcn_mfma_f32_16x16x32_bf16(ck2, AQ, zz, 0, 0, 0);      \
        f32x4 s3 = __builtin_amdgcn_mfma_f32_16x16x32_bf16(ck3, AQ, zz, 0, 0, 0);      \
        bf16x8 P1 = {(__bf16)FEXP2(s2[0]), (__bf16)FEXP2(s2[1]),                       \
                     (__bf16)FEXP2(s2[2]), (__bf16)FEXP2(s2[3]),                       \
                     (__bf16)FEXP2(s3[0]), (__bf16)FEXP2(s3[1]),                       \
                     (__bf16)FEXP2(s3[2]), (__bf16)FEXP2(s3[3])};                      \
        O0R = __builtin_amdgcn_mfma_f32_16x16x32_bf16(vv01, P1, O0R, 0, 0, 0);         \
        O1R = __builtin_amdgcn_mfma_f32_16x16x32_bf16(vv11, P1, O1R, 0, 0, 0);         \
        LAR = __builtin_amdgcn_mfma_f32_16x16x32_bf16(ones, P1, LAR, 0, 0, 0);         \
    } while (0)

#define COMPUTE(CUR) do {                                                              \
        const __bf16* Kb = &Kl[CUR][0][0];                                             \
        const __bf16* Vb = &Vl[CUR][0][0];                                             \
        const bf16x8 ck0 = *(const bf16x8*)(Kb + (      col) * 32 + g * 8);            \
        const bf16x8 ck1 = *(const bf16x8*)(Kb + (16 + col) * 32 + g * 8);             \
        const bf16x8 ck2 = *(const bf16x8*)(Kb + (32 + col) * 32 + g * 8);             \
        const bf16x8 ck3 = *(const bf16x8*)(Kb + (48 + col) * 32 + g * 8);             \
        const bf16x8 vv00 = *(const bf16x8*)(Vb + (      col) * 72      + g * 8);      \
        const bf16x8 vv01 = *(const bf16x8*)(Vb + (      col) * 72 + 32 + g * 8);      \
        const bf16x8 vv10 = *(const bf16x8*)(Vb + (16 + col) * 72      + g * 8);       \
        const bf16x8 vv11 = *(const bf16x8*)(Vb + (16 + col) * 72 + 32 + g * 8);       \
        const f32x4 zz = {0.f, 0.f, 0.f, 0.f};                                         \
        SQH(aq0, O00, O01, La0);                                                       \
        SQH(aq1, O10, O11, La1);                                                       \
        SQH(aq2, O20, O21, La2);                                                       \
        SQH(aq3, O30, O31, La3);                                                       \
    } while (0)

    STAGE(0, cs);
    __syncthreads();
    for (int cc = cs; cc < ce; ++cc) {
        const int cur = (cc - cs) & 1;
        if (cc + 1 < ce) STAGE(cur ^ 1, cc + 1);   // overlaps with compute(cur)
        COMPUTE(cur);
        __syncthreads();                           // staging done + cur consumed
    }
#undef STAGE
#undef SQH
#undef COMPUTE

    if (!valid) return;
    const int t = bh * 49 + qt;
    __bf16* po = pO + ((size_t)t * NSPLIT + sp) * 64 * 32;
    float* plp = pl + ((size_t)t * NSPLIT + sp) * 64;
#define STQH(QH, O0R, O1R, LAR) do {                                                   \
        bf16x4 v0 = {(__bf16)O0R[0], (__bf16)O0R[1], (__bf16)O0R[2], (__bf16)O0R[3]};  \
        bf16x4 v1 = {(__bf16)O1R[0], (__bf16)O1R[1], (__bf16)O1R[2], (__bf16)O1R[3]};  \
        *(bf16x4*)(po + ((QH) * 16 + col) * 32      + g * 4) = v0;                     \
        *(bf16x4*)(po + ((QH) * 16 + col) * 32 + 16 + g * 4) = v1;                     \
        if (g == 0) plp[(QH) * 16 + col] = LAR[0];                                     \
    } while (0)
    STQH(0, O00, O01, La0);
    STQH(1, O10, O11, La1);
    STQH(2, O20, O21, La2);
    STQH(3, O30, O31, La3);
#undef STQH
}

// ---------------------------------------------------------------------------
// K3: reduce 8 split partials + normalize + LePE + bias -> attnT.  (R10 kernel)
// ---------------------------------------------------------------------------
__global__ __launch_bounds__(256) void k_reduce(
    const __bf16* __restrict__ pO, const float* __restrict__ pl,
    const __bf16* __restrict__ vT,
    const float* __restrict__ lepe_w, const float* __restrict__ lepe_b,
    __bf16* __restrict__ attnT)
{
    __shared__ float wl[32][25];
    __shared__ float bl[32];
    const int tid = threadIdx.x;
    const int qt = blockIdx.x, bh = blockIdx.y;
    const int b = bh >> 2, h = bh & 3;
    const int c0h = h * HD;

    for (int i = tid; i < 800; i += 256) ((float*)wl)[i] = lepe_w[c0h * 25 + i];
    if (tid < 32) bl[tid] = lepe_b[c0h + tid];
    __syncthreads();

    const int q  = tid >> 2;                   // 0..63
    const int dg = (tid & 3) * 8;              // 0,8,16,24
    const size_t t = (size_t)bh * 49 + qt;

    float lt = 0.f;
    float o[8] = {0.f, 0.f, 0.f, 0.f, 0.f, 0.f, 0.f, 0.f};
    #pragma unroll
    for (int s = 0; s < NSPLIT; ++s) {
        lt += pl[(t * NSPLIT + s) * 64 + q];
        const bf16x8 pv = *(const bf16x8*)(pO + ((t * NSPLIT + s) * 64 + q) * 32 + dg);
        #pragma unroll
        for (int i = 0; i < 8; ++i) o[i] += (float)pv[i];
    }
    const float linv = 1.0f / lt;
    #pragma unroll
    for (int i = 0; i < 8; ++i) o[i] = o[i] * linv + bl[dg + i];

    const int px = qt * 64 + q;
    const int py = px / WIMG, pxx = px % WIMG;
    const __bf16* vtb = vT + ((size_t)b * NPIX) * CCH + c0h + dg;
    #pragma unroll
    for (int dy = 0; dy < 5; ++dy) {
        const int yy = py + dy - 2;
        if (yy < 0 || yy >= WIMG) continue;
        #pragma unroll
        for (int dx = 0; dx < 5; ++dx) {
            const int xx = pxx + dx - 2;
            if (xx < 0 || xx >= WIMG) continue;
            const bf16x8 vv = *(const bf16x8*)(vtb + (size_t)(yy * WIMG + xx) * CCH);
            const int tap = dy * 5 + dx;
            #pragma unroll
            for (int i = 0; i < 8; ++i) o[i] += (float)vv[i] * wl[dg + i][tap];
        }
    }
    bf16x8 ov = {(__bf16)o[0], (__bf16)o[1], (__bf16)o[2], (__bf16)o[3],
                 (__bf16)o[4], (__bf16)o[5], (__bf16)o[6], (__bf16)o[7]};
    *(bf16x8*)(attnT + ((size_t)(b * NPIX + px)) * CCH + c0h + dg) = ov;
}

// ---------------------------------------------------------------------------
// K4: out = proj_w @ (attn+lepe) + proj_b, bf16 MFMA, zero LDS.  (R10 kernel)
// ---------------------------------------------------------------------------
__global__ __launch_bounds__(256) void k_proj(
    const __bf16* __restrict__ attnT, const float* __restrict__ proj_w,
    const float* __restrict__ proj_b, float* __restrict__ out)
{
    const int tid = threadIdx.x;
    const int w = tid >> 6, lane = tid & 63;
    const int col = lane & 15, g = lane >> 4;
    const int px0 = blockIdx.x * 32 + (w >> 1) * 16;
    const int obase = blockIdx.y * 32 + (w & 1) * 16;
    const int b = blockIdx.z;

    const float* wrow = proj_w + (size_t)(obase + col) * CCH;
    const __bf16* abase = attnT + (size_t)(b * NPIX + px0) * CCH;

    f32x4 acc = {0.f, 0.f, 0.f, 0.f};
    #pragma unroll
    for (int ks = 0; ks < 4; ++ks) {
        const int c0 = ks * 32 + g * 8;
        const float4 wA = *(const float4*)(wrow + c0);
        const float4 wB = *(const float4*)(wrow + c0 + 4);
        bf16x8 af = {(__bf16)wA.x, (__bf16)wA.y, (__bf16)wA.z, (__bf16)wA.w,
                     (__bf16)wB.x, (__bf16)wB.y, (__bf16)wB.z, (__bf16)wB.w};
        const bf16x8 bf_ = *(const bf16x8*)(abase + (size_t)col * CCH + c0);
        acc = __builtin_amdgcn_mfma_f32_16x16x32_bf16(af, bf_, acc, 0, 0, 0);
    }

    const f32x4 pb = *(const f32x4*)(proj_b + obase + g * 4);
    #pragma unroll
    for (int r = 0; r < 4; ++r)
        out[(size_t)(b * CCH + obase + g * 4 + r) * NPIX + px0 + col] = acc[r] + pb[r];
}

// ---------------------------------------------------------------------------
extern "C" void kernel_launch(void* const* d_in, const int* in_sizes, int n_in,
                              void* d_out, int out_size, void* d_ws, size_t ws_size,
                              hipStream_t stream)
{
    const float* x      = (const float*)d_in[0];
    const float* qkv_w  = (const float*)d_in[1];
    const float* qkv_b  = (const float*)d_in[2];
    const float* lepe_w = (const float*)d_in[3];
    const float* lepe_b = (const float*)d_in[4];
    const float* proj_w = (const float*)d_in[5];
    const float* proj_b = (const float*)d_in[6];
    float* out = (float*)d_out;

    char* p = (char*)d_ws;                                   // ~22 MB total
    __bf16* qT    = (__bf16*)p;  p += (size_t)2 * NH * NPIX * HD * 2;       // 1.6 MB
    __bf16* kT    = (__bf16*)p;  p += (size_t)2 * NH * NPIX * HD * 2;       // 1.6 MB
    __bf16* vT    = (__bf16*)p;  p += (size_t)2 * NPIX * CCH * 2;           // 1.6 MB
    __bf16* vP    = (__bf16*)p;  p += (size_t)2 * CCH * NPIX * 2;           // 1.6 MB
    __bf16* attnT = (__bf16*)p;  p += (size_t)2 * NPIX * CCH * 2;           // 1.6 MB
    __bf16* pO    = (__bf16*)p;  p += (size_t)392 * NSPLIT * 64 * 32 * 2;   // 12.8 MB
    float*  pl    = (float*)p;                                              // 0.8 MB

    k_qkv   <<<dim3(98, 3, 2), dim3(256), 0, stream>>>(x, qkv_w, qkv_b, qT, kT, vT, vP);
    k_attn  <<<dim3(13, 8, 8), dim3(256), 0, stream>>>(qT, kT, vP, pO, pl);
    k_reduce<<<dim3(49, 8),    dim3(256), 0, stream>>>(pO, pl, vT, lepe_w, lepe_b, attnT);
    k_proj  <<<dim3(98, 4, 2), dim3(256), 0, stream>>>(attnT, proj_w, proj_b, out);
}

// Round 13
// 118.266 us; speedup vs baseline: 1.3979x; 1.0133x over previous
//
#include <hip/hip_runtime.h>

typedef __bf16 bf16x8 __attribute__((ext_vector_type(8)));
typedef __bf16 bf16x4 __attribute__((ext_vector_type(4)));
typedef float  f32x4  __attribute__((ext_vector_type(4)));

#define NPIX  3136      // 56*56 = 49*64 (no tails)
#define WIMG  56
#define CCH   128
#define NH    4
#define HD    32
#define NSPLIT 8        // key-splits per (head, 64q) tile
// 32^-0.5 * log2(e): q pre-scaled so softmax uses exp2 directly
#define QSCALE 0.2550565470841439f

#if __has_builtin(__builtin_amdgcn_exp2f)
#define FEXP2(x) __builtin_amdgcn_exp2f(x)
#else
#define FEXP2(x) __expf((x) * 0.6931471805599453f)
#endif

// MFMA 16x16x32 maps (HW-verified R1-R12):
//   A[m=lane&15][k=(lane>>4)*8+j]   B[k=(lane>>4)*8+j][n=lane&15]
//   D: col(n)=lane&15, row(m)=(lane>>4)*4+reg
// Transpose-free attention (R8-R12): S^T = MFMA(A=K-frag, B=Q-frag) with the
// pi key-slot permutation baked into kT/vP makes exp(S^T) regs the PV B-frags.
// R11 calibration: fixed harness overhead F ~= 79 us; kernels+gaps ~= 41 us.
// R13: reduce+LePE+proj fused into k_rproj (392 blocks, single-pass per
// thread -- NOT R6's 196-block head-loop shape). 3 launches total.

__device__ __forceinline__ int perm_inv(int k) {
    return (((k >> 5) & 1) * 2 + ((k >> 2) & 1)) * 16 + (((k >> 3) & 3) * 4) + (k & 3);
}

// ---------------------------------------------------------------------------
// K1: qkv = qkv_w @ x + qkv_b, bf16 MFMA (M=384, K=128, N=6272).  (R12 kernel)
// grid (98, 3, 2) = 588 blocks, block 256, 32-px tiles.
// ---------------------------------------------------------------------------
__global__ __launch_bounds__(256) void k_qkv(
    const float* __restrict__ x, const float* __restrict__ qkv_w,
    const float* __restrict__ qkv_b,
    __bf16* __restrict__ qT, __bf16* __restrict__ kT,
    __bf16* __restrict__ vT, __bf16* __restrict__ vP)
{
    __shared__ __bf16 xl[32][136];                 // [px][c], row stride 272B
    const int tid = threadIdx.x;
    const int w = tid >> 6, lane = tid & 63;
    const int col = lane & 15, g = lane >> 4;
    const int px0 = blockIdx.x * 32;
    const int slab = blockIdx.y;                   // 0 q, 1 k, 2 v
    const int b = blockIdx.z;
    const int obase = slab * 128 + w * 32;
    const int kbase = px0 & ~63;                   // pi 64-key block base
    const int khalf = px0 & 32;

    {   // stage x tile (coalesced 128B rows, packed b64 LDS writes)
        const int px = tid & 31, cq = tid >> 5;    // cq 0..7
        const float* xp = x + (size_t)b * CCH * NPIX + px0 + px;
        #pragma unroll
        for (int i = 0; i < 4; ++i) {
            const int c0 = cq * 4 + i * 32;
            const float v0 = xp[(size_t)(c0 + 0) * NPIX];
            const float v1 = xp[(size_t)(c0 + 1) * NPIX];
            const float v2 = xp[(size_t)(c0 + 2) * NPIX];
            const float v3 = xp[(size_t)(c0 + 3) * NPIX];
            bf16x4 bv = {(__bf16)v0, (__bf16)v1, (__bf16)v2, (__bf16)v3};
            *(bf16x4*)&xl[px][c0] = bv;
        }
    }
    __syncthreads();

    f32x4 acc[2][2];                               // [out tile][px tile]
    #pragma unroll
    for (int ot = 0; ot < 2; ++ot)
        #pragma unroll
        for (int a = 0; a < 2; ++a) acc[ot][a] = (f32x4){0.f, 0.f, 0.f, 0.f};

    #pragma unroll
    for (int ks = 0; ks < 4; ++ks) {
        const int c0 = ks * 32 + g * 8;
        #pragma unroll
        for (int ot = 0; ot < 2; ++ot) {
            const float* wrow = qkv_w + (size_t)(obase + ot * 16 + col) * CCH + c0;
            const float4 wA = *(const float4*)(wrow);
            const float4 wB = *(const float4*)(wrow + 4);
            bf16x8 af = {(__bf16)wA.x, (__bf16)wA.y, (__bf16)wA.z, (__bf16)wA.w,
                         (__bf16)wB.x, (__bf16)wB.y, (__bf16)wB.z, (__bf16)wB.w};
            #pragma unroll
            for (int a = 0; a < 2; ++a) {
                const bf16x8 bf_ = *(const bf16x8*)&xl[16 * a + col][c0];  // one b128
                acc[ot][a] = __builtin_amdgcn_mfma_f32_16x16x32_bf16(af, bf_, acc[ot][a], 0, 0, 0);
            }
        }
    }

    #pragma unroll
    for (int ot = 0; ot < 2; ++ot) {
        const int orow = obase + ot * 16 + g * 4;      // global output row
        const f32x4 bias4 = *(const f32x4*)(qkv_b + orow);
        if (slab == 0) {                               // ---- q (scaled) ----
            const int o = orow, h = o >> 5, d0 = o & 31;
            __bf16* dst = qT + ((size_t)(b * NH + h) * NPIX) * HD + d0;
            #pragma unroll
            for (int a = 0; a < 2; ++a) {
                const int px = px0 + 16 * a + col;
                bf16x4 v;
                #pragma unroll
                for (int r = 0; r < 4; ++r) v[r] = (__bf16)((acc[ot][a][r] + bias4[r]) * QSCALE);
                *(bf16x4*)(dst + (size_t)px * HD) = v;
            }
        } else if (slab == 1) {                        // ---- k (pi-permuted rows) ----
            const int o = orow - 128, h = o >> 5, d0 = o & 31;
            __bf16* dst = kT + ((size_t)(b * NH + h) * NPIX) * HD + d0;
            #pragma unroll
            for (int a = 0; a < 2; ++a) {
                const int s = perm_inv(khalf + 16 * a + col);  // slot for key kappa
                bf16x4 v;
                #pragma unroll
                for (int r = 0; r < 4; ++r) v[r] = (__bf16)(acc[ot][a][r] + bias4[r]);
                *(bf16x4*)(dst + (size_t)(kbase + s) * HD) = v;
            }
        } else {                                       // ---- v: vT + pi-permuted vP ----
            const int c = orow - 256;
            #pragma unroll
            for (int a = 0; a < 2; ++a) {
                const int px = px0 + 16 * a + col;
                const int s = perm_inv(khalf + 16 * a + col);
                bf16x4 v;
                #pragma unroll
                for (int r = 0; r < 4; ++r) v[r] = (__bf16)(acc[ot][a][r] + bias4[r]);
                *(bf16x4*)(vT + ((size_t)(b * NPIX + px)) * CCH + c) = v;
                #pragma unroll
                for (int r = 0; r < 4; ++r)
                    vP[((size_t)(b * CCH + c + r)) * NPIX + kbase + s] = v[r];
            }
        }
    }
}

// ---------------------------------------------------------------------------
// K2: attention partials, LDS-shared chunk stream, transpose-free. (R12 kernel)
// grid (13, 8, 8), block 256 = 4 waves; __launch_bounds__(256,4) for 16 w/CU.
// ---------------------------------------------------------------------------
__global__ __launch_bounds__(256, 4) void k_attn(
    const __bf16* __restrict__ qT, const __bf16* __restrict__ kT,
    const __bf16* __restrict__ vP,
    __bf16* __restrict__ pO, float* __restrict__ pl)
{
    __shared__ __bf16 Kl[2][64][32];       // [buf][slot][d] -- source layout
    __shared__ __bf16 Vl[2][32][72];       // [buf][d][slot], +8 pad

    const int tid = threadIdx.x;
    const int w = tid >> 6, lane = tid & 63;
    const int col = lane & 15, g = lane >> 4;
    const int qt = blockIdx.x * 4 + w;          // 0..51; 49..51 idle
    const bool valid = qt < 49;
    const int qtc = valid ? qt : 48;
    const int bh = blockIdx.y, sp = blockIdx.z;
    const int b = bh >> 2, h = bh & 3;
    const int qbase = qtc * 64;
    const size_t headoff = (size_t)bh * NPIX * HD;
    const int c0h = h * HD;

    const __bf16* qbp = qT + headoff + (size_t)(qbase + col) * HD + g * 8;
    const bf16x8 aq0 = *(const bf16x8*)(qbp);
    const bf16x8 aq1 = *(const bf16x8*)(qbp + 16 * HD);
    const bf16x8 aq2 = *(const bf16x8*)(qbp + 32 * HD);
    const bf16x8 aq3 = *(const bf16x8*)(qbp + 48 * HD);

    const __bf16 one = (__bf16)1.0f;
    const bf16x8 ones = {one, one, one, one, one, one, one, one};

    f32x4 O00 = {0,0,0,0}, O01 = {0,0,0,0}, O10 = {0,0,0,0}, O11 = {0,0,0,0};
    f32x4 O20 = {0,0,0,0}, O21 = {0,0,0,0}, O30 = {0,0,0,0}, O31 = {0,0,0,0};
    f32x4 La0 = {0,0,0,0}, La1 = {0,0,0,0}, La2 = {0,0,0,0}, La3 = {0,0,0,0};

    const __bf16* kTh = kT + headoff;
    const int vr = tid >> 3;                    // 0..31 (d row)
    const int vo = (tid & 7) * 8;               // elem offset within chunk
    const __bf16* vsrc = vP + (size_t)(b * CCH + c0h + vr) * NPIX + vo;

    const int cs = (49 * sp) >> 3, ce = (49 * (sp + 1)) >> 3;   // 6 or 7 chunks

#define STAGE(BUF, CHUNK) do { const int _k0 = (CHUNK) * 64;                           \
        *(bf16x8*)(&Kl[BUF][0][0] + tid * 8) =                                         \
            *(const bf16x8*)(kTh + (size_t)_k0 * HD + tid * 8);                        \
        *(bf16x8*)(&Vl[BUF][vr][vo]) = *(const bf16x8*)(vsrc + _k0);                   \
    } while (0)

    // low-transient SQH: s0/s1 -> P0 retired before s2/s3 computed
#define SQH(AQ, O0R, O1R, LAR)  do {                                                   \
        f32x4 s0 = __builtin_amdgcn_mfma_f32_16x16x32_bf16(ck0, AQ, zz, 0, 0, 0);      \
        f32x4 s1 = __builtin_amdgcn_mfma_f32_16x16x32_bf16(ck1, AQ, zz, 0, 0, 0);      \
        bf16x8 P0 = {(__bf16)FEXP2(s0[0]), (__bf16)FEXP2(s0[1]),                       \
                     (__bf16)FEXP2(s0[2]), (__bf16)FEXP2(s0[3]),                       \
                     (__bf16)FEXP2(s1[0]), (__bf16)FEXP2(s1[1]),                       \
                     (__bf16)FEXP2(s1[2]), (__bf16)FEXP2(s1[3])};                      \
        O0R = __builtin_amdgcn_mfma_f32_16x16x32_bf16(vv00, P0, O0R, 0, 0, 0);         \
        O1R = __builtin_amdgcn_mfma_f32_16x16x32_bf16(vv10, P0, O1R, 0, 0, 0);         \
        LAR = __builtin_amdgcn_mfma_f32_16x16x32_bf16(ones, P0, LAR, 0, 0, 0);         \
        f32x4 s2 = __builtin_amdgcn_mfma_f32_16x16x32_bf16(ck2, AQ, zz, 0, 0, 0);      \
        f32x4 s3 = __builtin_amdgcn_mfma_f32_16x16x32_bf16(ck3, AQ, zz, 0, 0, 0);      \
        bf16x8 P1 = {(__bf16)FEXP2(s2[0]), (__bf16)FEXP2(s2[1]),                       \
                     (__bf16)FEXP2(s2[2]), (__bf16)FEXP2(s2[3]),                       \
                     (__bf16)FEXP2(s3[0]), (__bf16)FEXP2(s3[1]),                       \
                     (__bf16)FEXP2(s3[2]), (__bf16)FEXP2(s3[3])};                      \
        O0R = __builtin_amdgcn_mfma_f32_16x16x32_bf16(vv01, P1, O0R, 0, 0, 0);         \
        O1R = __builtin_amdgcn_mfma_f32_16x16x32_bf16(vv11, P1, O1R, 0, 0, 0);         \
        LAR = __builtin_amdgcn_mfma_f32_16x16x32_bf16(ones, P1, LAR, 0, 0, 0);         \
    } while (0)

#define COMPUTE(CUR) do {                                                              \
        const __bf16* Kb = &Kl[CUR][0][0];                                             \
        const __bf16* Vb = &Vl[CUR][0][0];                                             \
        const bf16x8 ck0 = *(const bf16x8*)(Kb + (      col) * 32 + g * 8);            \
        const bf16x8 ck1 = *(const bf16x8*)(Kb + (16 + col) * 32 + g * 8);             \
        const bf16x8 ck2 = *(const bf16x8*)(Kb + (32 + col) * 32 + g * 8);             \
        const bf16x8 ck3 = *(const bf16x8*)(Kb + (48 + col) * 32 + g * 8);             \
        const bf16x8 vv00 = *(const bf16x8*)(Vb + (      col) * 72      + g * 8);      \
        const bf16x8 vv01 = *(const bf16x8*)(Vb + (      col) * 72 + 32 + g * 8);      \
        const bf16x8 vv10 = *(const bf16x8*)(Vb + (16 + col) * 72      + g * 8);       \
        const bf16x8 vv11 = *(const bf16x8*)(Vb + (16 + col) * 72 + 32 + g * 8);       \
        const f32x4 zz = {0.f, 0.f, 0.f, 0.f};                                         \
        SQH(aq0, O00, O01, La0);                                                       \
        SQH(aq1, O10, O11, La1);                                                       \
        SQH(aq2, O20, O21, La2);                                                       \
        SQH(aq3, O30, O31, La3);                                                       \
    } while (0)

    STAGE(0, cs);
    __syncthreads();
    for (int cc = cs; cc < ce; ++cc) {
        const int cur = (cc - cs) & 1;
        if (cc + 1 < ce) STAGE(cur ^ 1, cc + 1);   // overlaps with compute(cur)
        COMPUTE(cur);
        __syncthreads();                           // staging done + cur consumed
    }
#undef STAGE
#undef SQH
#undef COMPUTE

    if (!valid) return;
    const int t = bh * 49 + qt;
    __bf16* po = pO + ((size_t)t * NSPLIT + sp) * 64 * 32;
    float* plp = pl + ((size_t)t * NSPLIT + sp) * 64;
#define STQH(QH, O0R, O1R, LAR) do {                                                   \
        bf16x4 v0 = {(__bf16)O0R[0], (__bf16)O0R[1], (__bf16)O0R[2], (__bf16)O0R[3]};  \
        bf16x4 v1 = {(__bf16)O1R[0], (__bf16)O1R[1], (__bf16)O1R[2], (__bf16)O1R[3]};  \
        *(bf16x4*)(po + ((QH) * 16 + col) * 32      + g * 4) = v0;                     \
        *(bf16x4*)(po + ((QH) * 16 + col) * 32 + 16 + g * 4) = v1;                     \
        if (g == 0) plp[(QH) * 16 + col] = LAR[0];                                     \
    } while (0)
    STQH(0, O00, O01, La0);
    STQH(1, O10, O11, La1);
    STQH(2, O20, O21, La2);
    STQH(3, O30, O31, La3);
#undef STQH
}

// ---------------------------------------------------------------------------
// K3 (NEW): fused reduce + LePE + proj. grid (196, 2) = 392 blocks, block 256.
// Block = 16 px x all 128 channels. Phase 1: each thread (px, 8-ch group,
// single head via its channels) sums 8 split partials, normalizes, adds
// LePE+bias -> LDS at[16][136]. Phase 2: proj MFMA straight from LDS.
// Unlike R6's failed fusion: no per-thread head loop, 2x blocks, 1-pass VMEM.
// ---------------------------------------------------------------------------
__global__ __launch_bounds__(256) void k_rproj(
    const __bf16* __restrict__ pO, const float* __restrict__ pl,
    const __bf16* __restrict__ vT,
    const float* __restrict__ lepe_w, const float* __restrict__ lepe_b,
    const float* __restrict__ proj_w, const float* __restrict__ proj_b,
    float* __restrict__ out)
{
    __shared__ __bf16 at[16][136];         // reduced attn+lepe tile [px][c], +8 pad
    __shared__ float  wl[CCH][25];
    __shared__ float  bl[CCH];
    const int tid = threadIdx.x;
    const int pb = blockIdx.x;             // 0..195 (16-px tile)
    const int b  = blockIdx.y;
    const int qt = pb >> 2;                // 64-q supertile (pO granularity)
    const int qs = (pb & 3) * 16;          // px offset within supertile
    const int px0 = qt * 64 + qs;

    for (int i = tid; i < CCH * 25; i += 256) ((float*)wl)[i] = lepe_w[i];
    if (tid < CCH) bl[tid] = lepe_b[tid];
    __syncthreads();

    // ---- phase 1: thread = (px 0..15, 8-channel group 0..15) ----
    {
        const int px = tid >> 4;           // 0..15
        const int cg = (tid & 15) * 8;     // 0..120 (global channel base)
        const int h  = cg >> 5;            // this thread's head
        const int dg = cg & 31;            // d within head
        const int q  = qs + px;            // q index within 64-q supertile
        const size_t t = (size_t)(b * NH + h) * 49 + qt;

        float lt = 0.f;
        float o[8] = {0.f, 0.f, 0.f, 0.f, 0.f, 0.f, 0.f, 0.f};
        #pragma unroll
        for (int s = 0; s < NSPLIT; ++s) {
            lt += pl[(t * NSPLIT + s) * 64 + q];
            const bf16x8 pv = *(const bf16x8*)(pO + ((t * NSPLIT + s) * 64 + q) * 32 + dg);
            #pragma unroll
            for (int i = 0; i < 8; ++i) o[i] += (float)pv[i];
        }
        const float linv = 1.0f / lt;
        #pragma unroll
        for (int i = 0; i < 8; ++i) o[i] = o[i] * linv + bl[cg + i];

        const int P = px0 + px;
        const int py = P / WIMG, pxx = P % WIMG;
        const __bf16* vtb = vT + ((size_t)b * NPIX) * CCH + cg;
        #pragma unroll
        for (int dy = 0; dy < 5; ++dy) {
            const int yy = py + dy - 2;
            if (yy < 0 || yy >= WIMG) continue;
            #pragma unroll
            for (int dx = 0; dx < 5; ++dx) {
                const int xx = pxx + dx - 2;
                if (xx < 0 || xx >= WIMG) continue;
                const bf16x8 vv = *(const bf16x8*)(vtb + (size_t)(yy * WIMG + xx) * CCH);
                const int tap = dy * 5 + dx;
                #pragma unroll
                for (int i = 0; i < 8; ++i) o[i] += (float)vv[i] * wl[cg + i][tap];
            }
        }
        bf16x8 ov = {(__bf16)o[0], (__bf16)o[1], (__bf16)o[2], (__bf16)o[3],
                     (__bf16)o[4], (__bf16)o[5], (__bf16)o[6], (__bf16)o[7]};
        *(bf16x8*)&at[px][cg] = ov;
    }
    __syncthreads();

    // ---- phase 2: proj. wave w -> outputs [w*32, w*32+32), px = col ----
    const int w = tid >> 6, lane = tid & 63;
    const int col = lane & 15, g = lane >> 4;
    const int obase = w * 32;

    #pragma unroll
    for (int ot = 0; ot < 2; ++ot) {
        const float* wrow = proj_w + (size_t)(obase + ot * 16 + col) * CCH;
        f32x4 acc = {0.f, 0.f, 0.f, 0.f};
        #pragma unroll
        for (int ks = 0; ks < 4; ++ks) {
            const int c0 = ks * 32 + g * 8;
            const float4 wA = *(const float4*)(wrow + c0);
            const float4 wB = *(const float4*)(wrow + c0 + 4);
            bf16x8 af = {(__bf16)wA.x, (__bf16)wA.y, (__bf16)wA.z, (__bf16)wA.w,
                         (__bf16)wB.x, (__bf16)wB.y, (__bf16)wB.z, (__bf16)wB.w};
            const bf16x8 bf_ = *(const bf16x8*)&at[col][c0];   // one b128
            acc = __builtin_amdgcn_mfma_f32_16x16x32_bf16(af, bf_, acc, 0, 0, 0);
        }
        const f32x4 pb4 = *(const f32x4*)(proj_b + obase + ot * 16 + g * 4);
        #pragma unroll
        for (int r = 0; r < 4; ++r)
            out[(size_t)(b * CCH + obase + ot * 16 + g * 4 + r) * NPIX + px0 + col] =
                acc[r] + pb4[r];
    }
}

// ---------------------------------------------------------------------------
extern "C" void kernel_launch(void* const* d_in, const int* in_sizes, int n_in,
                              void* d_out, int out_size, void* d_ws, size_t ws_size,
                              hipStream_t stream)
{
    const float* x      = (const float*)d_in[0];
    const float* qkv_w  = (const float*)d_in[1];
    const float* qkv_b  = (const float*)d_in[2];
    const float* lepe_w = (const float*)d_in[3];
    const float* lepe_b = (const float*)d_in[4];
    const float* proj_w = (const float*)d_in[5];
    const float* proj_b = (const float*)d_in[6];
    float* out = (float*)d_out;

    char* p = (char*)d_ws;                                   // ~20 MB total
    __bf16* qT = (__bf16*)p;  p += (size_t)2 * NH * NPIX * HD * 2;       // 1.6 MB
    __bf16* kT = (__bf16*)p;  p += (size_t)2 * NH * NPIX * HD * 2;       // 1.6 MB
    __bf16* vT = (__bf16*)p;  p += (size_t)2 * NPIX * CCH * 2;           // 1.6 MB
    __bf16* vP = (__bf16*)p;  p += (size_t)2 * CCH * NPIX * 2;           // 1.6 MB
    __bf16* pO = (__bf16*)p;  p += (size_t)392 * NSPLIT * 64 * 32 * 2;   // 12.8 MB
    float*  pl = (float*)p;                                              // 0.8 MB

    k_qkv  <<<dim3(98, 3, 2), dim3(256), 0, stream>>>(x, qkv_w, qkv_b, qT, kT, vT, vP);
    k_attn <<<dim3(13, 8, 8), dim3(256), 0, stream>>>(qT, kT, vP, pO, pl);
    k_rproj<<<dim3(196, 2),   dim3(256), 0, stream>>>(pO, pl, vT, lepe_w, lepe_b,
                                                      proj_w, proj_b, out);
}

// Round 15
// 116.814 us; speedup vs baseline: 1.4152x; 1.0124x over previous
//
#include <hip/hip_runtime.h>

typedef __bf16 bf16x8 __attribute__((ext_vector_type(8)));
typedef __bf16 bf16x4 __attribute__((ext_vector_type(4)));
typedef float  f32x4  __attribute__((ext_vector_type(4)));

#define NPIX  3136      // 56*56 = 49*64 (no tails)
#define WIMG  56
#define CCH   128
#define NH    4
#define HD    32
#define NSPLIT 8        // key-splits per (head, 64q) tile
// 32^-0.5 * log2(e): q pre-scaled so softmax uses exp2 directly
#define QSCALE 0.2550565470841439f

#if __has_builtin(__builtin_amdgcn_exp2f)
#define FEXP2(x) __builtin_amdgcn_exp2f(x)
#else
#define FEXP2(x) __expf((x) * 0.6931471805599453f)
#endif

// MFMA 16x16x32 maps (HW-verified R1-R13):
//   A[m=lane&15][k=(lane>>4)*8+j]   B[k=(lane>>4)*8+j][n=lane&15]
//   D: col(n)=lane&15, row(m)=(lane>>4)*4+reg
// Transpose-free attention (R8-R13): S^T = MFMA(A=K-frag, B=Q-frag) with the
// pi key-slot permutation baked into kT/vP makes exp(S^T) regs the PV B-frags.
// R11 calibration: fixed harness overhead F ~= 79 us; kernels+gaps ~= 39 us.
// R14 lesson: hipLaunchCooperativeKernel silently no-ops under this harness's
// graph capture -- plain <<<>>> stream launches only.
// R15 = R13 verbatim (best verified state, 118.3 us).

__device__ __forceinline__ int perm_inv(int k) {
    return (((k >> 5) & 1) * 2 + ((k >> 2) & 1)) * 16 + (((k >> 3) & 3) * 4) + (k & 3);
}

// ---------------------------------------------------------------------------
// K1: qkv = qkv_w @ x + qkv_b, bf16 MFMA (M=384, K=128, N=6272).
// grid (98, 3, 2) = 588 blocks, block 256, 32-px tiles.
// ---------------------------------------------------------------------------
__global__ __launch_bounds__(256) void k_qkv(
    const float* __restrict__ x, const float* __restrict__ qkv_w,
    const float* __restrict__ qkv_b,
    __bf16* __restrict__ qT, __bf16* __restrict__ kT,
    __bf16* __restrict__ vT, __bf16* __restrict__ vP)
{
    __shared__ __bf16 xl[32][136];                 // [px][c], row stride 272B
    const int tid = threadIdx.x;
    const int w = tid >> 6, lane = tid & 63;
    const int col = lane & 15, g = lane >> 4;
    const int px0 = blockIdx.x * 32;
    const int slab = blockIdx.y;                   // 0 q, 1 k, 2 v
    const int b = blockIdx.z;
    const int obase = slab * 128 + w * 32;
    const int kbase = px0 & ~63;                   // pi 64-key block base
    const int khalf = px0 & 32;

    {   // stage x tile (coalesced 128B rows, packed b64 LDS writes)
        const int px = tid & 31, cq = tid >> 5;    // cq 0..7
        const float* xp = x + (size_t)b * CCH * NPIX + px0 + px;
        #pragma unroll
        for (int i = 0; i < 4; ++i) {
            const int c0 = cq * 4 + i * 32;
            const float v0 = xp[(size_t)(c0 + 0) * NPIX];
            const float v1 = xp[(size_t)(c0 + 1) * NPIX];
            const float v2 = xp[(size_t)(c0 + 2) * NPIX];
            const float v3 = xp[(size_t)(c0 + 3) * NPIX];
            bf16x4 bv = {(__bf16)v0, (__bf16)v1, (__bf16)v2, (__bf16)v3};
            *(bf16x4*)&xl[px][c0] = bv;
        }
    }
    __syncthreads();

    f32x4 acc[2][2];                               // [out tile][px tile]
    #pragma unroll
    for (int ot = 0; ot < 2; ++ot)
        #pragma unroll
        for (int a = 0; a < 2; ++a) acc[ot][a] = (f32x4){0.f, 0.f, 0.f, 0.f};

    #pragma unroll
    for (int ks = 0; ks < 4; ++ks) {
        const int c0 = ks * 32 + g * 8;
        #pragma unroll
        for (int ot = 0; ot < 2; ++ot) {
            const float* wrow = qkv_w + (size_t)(obase + ot * 16 + col) * CCH + c0;
            const float4 wA = *(const float4*)(wrow);
            const float4 wB = *(const float4*)(wrow + 4);
            bf16x8 af = {(__bf16)wA.x, (__bf16)wA.y, (__bf16)wA.z, (__bf16)wA.w,
                         (__bf16)wB.x, (__bf16)wB.y, (__bf16)wB.z, (__bf16)wB.w};
            #pragma unroll
            for (int a = 0; a < 2; ++a) {
                const bf16x8 bf_ = *(const bf16x8*)&xl[16 * a + col][c0];  // one b128
                acc[ot][a] = __builtin_amdgcn_mfma_f32_16x16x32_bf16(af, bf_, acc[ot][a], 0, 0, 0);
            }
        }
    }

    #pragma unroll
    for (int ot = 0; ot < 2; ++ot) {
        const int orow = obase + ot * 16 + g * 4;      // global output row
        const f32x4 bias4 = *(const f32x4*)(qkv_b + orow);
        if (slab == 0) {                               // ---- q (scaled) ----
            const int o = orow, h = o >> 5, d0 = o & 31;
            __bf16* dst = qT + ((size_t)(b * NH + h) * NPIX) * HD + d0;
            #pragma unroll
            for (int a = 0; a < 2; ++a) {
                const int px = px0 + 16 * a + col;
                bf16x4 v;
                #pragma unroll
                for (int r = 0; r < 4; ++r) v[r] = (__bf16)((acc[ot][a][r] + bias4[r]) * QSCALE);
                *(bf16x4*)(dst + (size_t)px * HD) = v;
            }
        } else if (slab == 1) {                        // ---- k (pi-permuted rows) ----
            const int o = orow - 128, h = o >> 5, d0 = o & 31;
            __bf16* dst = kT + ((size_t)(b * NH + h) * NPIX) * HD + d0;
            #pragma unroll
            for (int a = 0; a < 2; ++a) {
                const int s = perm_inv(khalf + 16 * a + col);  // slot for key kappa
                bf16x4 v;
                #pragma unroll
                for (int r = 0; r < 4; ++r) v[r] = (__bf16)(acc[ot][a][r] + bias4[r]);
                *(bf16x4*)(dst + (size_t)(kbase + s) * HD) = v;
            }
        } else {                                       // ---- v: vT + pi-permuted vP ----
            const int c = orow - 256;
            #pragma unroll
            for (int a = 0; a < 2; ++a) {
                const int px = px0 + 16 * a + col;
                const int s = perm_inv(khalf + 16 * a + col);
                bf16x4 v;
                #pragma unroll
                for (int r = 0; r < 4; ++r) v[r] = (__bf16)(acc[ot][a][r] + bias4[r]);
                *(bf16x4*)(vT + ((size_t)(b * NPIX + px)) * CCH + c) = v;
                #pragma unroll
                for (int r = 0; r < 4; ++r)
                    vP[((size_t)(b * CCH + c + r)) * NPIX + kbase + s] = v[r];
            }
        }
    }
}

// ---------------------------------------------------------------------------
// K2: attention partials, LDS-shared chunk stream, transpose-free.
// grid (13, 8, 8), block 256 = 4 waves; __launch_bounds__(256,4) for 16 w/CU.
// ---------------------------------------------------------------------------
__global__ __launch_bounds__(256, 4) void k_attn(
    const __bf16* __restrict__ qT, const __bf16* __restrict__ kT,
    const __bf16* __restrict__ vP,
    __bf16* __restrict__ pO, float* __restrict__ pl)
{
    __shared__ __bf16 Kl[2][64][32];       // [buf][slot][d] -- source layout
    __shared__ __bf16 Vl[2][32][72];       // [buf][d][slot], +8 pad

    const int tid = threadIdx.x;
    const int w = tid >> 6, lane = tid & 63;
    const int col = lane & 15, g = lane >> 4;
    const int qt = blockIdx.x * 4 + w;          // 0..51; 49..51 idle
    const bool valid = qt < 49;
    const int qtc = valid ? qt : 48;
    const int bh = blockIdx.y, sp = blockIdx.z;
    const int b = bh >> 2, h = bh & 3;
    const int qbase = qtc * 64;
    const size_t headoff = (size_t)bh * NPIX * HD;
    const int c0h = h * HD;

    const __bf16* qbp = qT + headoff + (size_t)(qbase + col) * HD + g * 8;
    const bf16x8 aq0 = *(const bf16x8*)(qbp);
    const bf16x8 aq1 = *(const bf16x8*)(qbp + 16 * HD);
    const bf16x8 aq2 = *(const bf16x8*)(qbp + 32 * HD);
    const bf16x8 aq3 = *(const bf16x8*)(qbp + 48 * HD);

    const __bf16 one = (__bf16)1.0f;
    const bf16x8 ones = {one, one, one, one, one, one, one, one};

    f32x4 O00 = {0,0,0,0}, O01 = {0,0,0,0}, O10 = {0,0,0,0}, O11 = {0,0,0,0};
    f32x4 O20 = {0,0,0,0}, O21 = {0,0,0,0}, O30 = {0,0,0,0}, O31 = {0,0,0,0};
    f32x4 La0 = {0,0,0,0}, La1 = {0,0,0,0}, La2 = {0,0,0,0}, La3 = {0,0,0,0};

    const __bf16* kTh = kT + headoff;
    const int vr = tid >> 3;                    // 0..31 (d row)
    const int vo = (tid & 7) * 8;               // elem offset within chunk
    const __bf16* vsrc = vP + (size_t)(b * CCH + c0h + vr) * NPIX + vo;

    const int cs = (49 * sp) >> 3, ce = (49 * (sp + 1)) >> 3;   // 6 or 7 chunks

#define STAGE(BUF, CHUNK) do { const int _k0 = (CHUNK) * 64;                           \
        *(bf16x8*)(&Kl[BUF][0][0] + tid * 8) =                                         \
            *(const bf16x8*)(kTh + (size_t)_k0 * HD + tid * 8);                        \
        *(bf16x8*)(&Vl[BUF][vr][vo]) = *(const bf16x8*)(vsrc + _k0);                   \
    } while (0)

    // low-transient SQH: s0/s1 -> P0 retired before s2/s3 computed
#define SQH(AQ, O0R, O1R, LAR)  do {                                                   \
        f32x4 s0 = __builtin_amdgcn_mfma_f32_16x16x32_bf16(ck0, AQ, zz, 0, 0, 0);      \
        f32x4 s1 = __builtin_amdgcn_mfma_f32_16x16x32_bf16(ck1, AQ, zz, 0, 0, 0);      \
        bf16x8 P0 = {(__bf16)FEXP2(s0[0]), (__bf16)FEXP2(s0[1]),                       \
                     (__bf16)FEXP2(s0[2]), (__bf16)FEXP2(s0[3]),                       \
                     (__bf16)FEXP2(s1[0]), (__bf16)FEXP2(s1[1]),                       \
                     (__bf16)FEXP2(s1[2]), (__bf16)FEXP2(s1[3])};                      \
        O0R = __builtin_amdgcn_mfma_f32_16x16x32_bf16(vv00, P0, O0R, 0, 0, 0);         \
        O1R = __builtin_amdgcn_mfma_f32_16x16x32_bf16(vv10, P0, O1R, 0, 0, 0);         \
        LAR = __builtin_amdgcn_mfma_f32_16x16x32_bf16(ones, P0, LAR, 0, 0, 0);         \
        f32x4 s2 = __builtin_amdgcn_mfma_f32_16x16x32_bf16(ck2, AQ, zz, 0, 0, 0);      \
        f32x4 s3 = __builtin_amdgcn_mfma_f32_16x16x32_bf16(ck3, AQ, zz, 0, 0, 0);      \
        bf16x8 P1 = {(__bf16)FEXP2(s2[0]), (__bf16)FEXP2(s2[1]),                       \
                     (__bf16)FEXP2(s2[2]), (__bf16)FEXP2(s2[3]),                       \
                     (__bf16)FEXP2(s3[0]), (__bf16)FEXP2(s3[1]),                       \
                     (__bf16)FEXP2(s3[2]), (__bf16)FEXP2(s3[3])};                      \
        O0R = __builtin_amdgcn_mfma_f32_16x16x32_bf16(vv01, P1, O0R, 0, 0, 0);         \
        O1R = __builtin_amdgcn_mfma_f32_16x16x32_bf16(vv11, P1, O1R, 0, 0, 0);         \
        LAR = __builtin_amdgcn_mfma_f32_16x16x32_bf16(ones, P1, LAR, 0, 0, 0);         \
    } while (0)

#define COMPUTE(CUR) do {                                                              \
        const __bf16* Kb = &Kl[CUR][0][0];                                             \
        const __bf16* Vb = &Vl[CUR][0][0];                                             \
        const bf16x8 ck0 = *(const bf16x8*)(Kb + (      col) * 32 + g * 8);            \
        const bf16x8 ck1 = *(const bf16x8*)(Kb + (16 + col) * 32 + g * 8);             \
        const bf16x8 ck2 = *(const bf16x8*)(Kb + (32 + col) * 32 + g * 8);             \
        const bf16x8 ck3 = *(const bf16x8*)(Kb + (48 + col) * 32 + g * 8);             \
        const bf16x8 vv00 = *(const bf16x8*)(Vb + (      col) * 72      + g * 8);      \
        const bf16x8 vv01 = *(const bf16x8*)(Vb + (      col) * 72 + 32 + g * 8);      \
        const bf16x8 vv10 = *(const bf16x8*)(Vb + (16 + col) * 72      + g * 8);       \
        const bf16x8 vv11 = *(const bf16x8*)(Vb + (16 + col) * 72 + 32 + g * 8);       \
        const f32x4 zz = {0.f, 0.f, 0.f, 0.f};                                         \
        SQH(aq0, O00, O01, La0);                                                       \
        SQH(aq1, O10, O11, La1);                                                       \
        SQH(aq2, O20, O21, La2);                                                       \
        SQH(aq3, O30, O31, La3);                                                       \
    } while (0)

    STAGE(0, cs);
    __syncthreads();
    for (int cc = cs; cc < ce; ++cc) {
        const int cur = (cc - cs) & 1;
        if (cc + 1 < ce) STAGE(cur ^ 1, cc + 1);   // overlaps with compute(cur)
        COMPUTE(cur);
        __syncthreads();                           // staging done + cur consumed
    }
#undef STAGE
#undef SQH
#undef COMPUTE

    if (!valid) return;
    const int t = bh * 49 + qt;
    __bf16* po = pO + ((size_t)t * NSPLIT + sp) * 64 * 32;
    float* plp = pl + ((size_t)t * NSPLIT + sp) * 64;
#define STQH(QH, O0R, O1R, LAR) do {                                                   \
        bf16x4 v0 = {(__bf16)O0R[0], (__bf16)O0R[1], (__bf16)O0R[2], (__bf16)O0R[3]};  \
        bf16x4 v1 = {(__bf16)O1R[0], (__bf16)O1R[1], (__bf16)O1R[2], (__bf16)O1R[3]};  \
        *(bf16x4*)(po + ((QH) * 16 + col) * 32      + g * 4) = v0;                     \
        *(bf16x4*)(po + ((QH) * 16 + col) * 32 + 16 + g * 4) = v1;                     \
        if (g == 0) plp[(QH) * 16 + col] = LAR[0];                                     \
    } while (0)
    STQH(0, O00, O01, La0);
    STQH(1, O10, O11, La1);
    STQH(2, O20, O21, La2);
    STQH(3, O30, O31, La3);
#undef STQH
}

// ---------------------------------------------------------------------------
// K3: fused reduce + LePE + proj. grid (196, 2) = 392 blocks, block 256.
// Block = 16 px x all 128 channels. Phase 1: each thread (px, 8-ch group,
// single head via its channels) sums 8 split partials, normalizes, adds
// LePE+bias -> LDS at[16][136]. Phase 2: proj MFMA straight from LDS.
// ---------------------------------------------------------------------------
__global__ __launch_bounds__(256) void k_rproj(
    const __bf16* __restrict__ pO, const float* __restrict__ pl,
    const __bf16* __restrict__ vT,
    const float* __restrict__ lepe_w, const float* __restrict__ lepe_b,
    const float* __restrict__ proj_w, const float* __restrict__ proj_b,
    float* __restrict__ out)
{
    __shared__ __bf16 at[16][136];         // reduced attn+lepe tile [px][c], +8 pad
    __shared__ float  wl[CCH][25];
    __shared__ float  bl[CCH];
    const int tid = threadIdx.x;
    const int pb = blockIdx.x;             // 0..195 (16-px tile)
    const int b  = blockIdx.y;
    const int qt = pb >> 2;                // 64-q supertile (pO granularity)
    const int qs = (pb & 3) * 16;          // px offset within supertile
    const int px0 = qt * 64 + qs;

    for (int i = tid; i < CCH * 25; i += 256) ((float*)wl)[i] = lepe_w[i];
    if (tid < CCH) bl[tid] = lepe_b[tid];
    __syncthreads();

    // ---- phase 1: thread = (px 0..15, 8-channel group 0..15) ----
    {
        const int px = tid >> 4;           // 0..15
        const int cg = (tid & 15) * 8;     // 0..120 (global channel base)
        const int h  = cg >> 5;            // this thread's head
        const int dg = cg & 31;            // d within head
        const int q  = qs + px;            // q index within 64-q supertile
        const size_t t = (size_t)(b * NH + h) * 49 + qt;

        float lt = 0.f;
        float o[8] = {0.f, 0.f, 0.f, 0.f, 0.f, 0.f, 0.f, 0.f};
        #pragma unroll
        for (int s = 0; s < NSPLIT; ++s) {
            lt += pl[(t * NSPLIT + s) * 64 + q];
            const bf16x8 pv = *(const bf16x8*)(pO + ((t * NSPLIT + s) * 64 + q) * 32 + dg);
            #pragma unroll
            for (int i = 0; i < 8; ++i) o[i] += (float)pv[i];
        }
        const float linv = 1.0f / lt;
        #pragma unroll
        for (int i = 0; i < 8; ++i) o[i] = o[i] * linv + bl[cg + i];

        const int P = px0 + px;
        const int py = P / WIMG, pxx = P % WIMG;
        const __bf16* vtb = vT + ((size_t)b * NPIX) * CCH + cg;
        #pragma unroll
        for (int dy = 0; dy < 5; ++dy) {
            const int yy = py + dy - 2;
            if (yy < 0 || yy >= WIMG) continue;
            #pragma unroll
            for (int dx = 0; dx < 5; ++dx) {
                const int xx = pxx + dx - 2;
                if (xx < 0 || xx >= WIMG) continue;
                const bf16x8 vv = *(const bf16x8*)(vtb + (size_t)(yy * WIMG + xx) * CCH);
                const int tap = dy * 5 + dx;
                #pragma unroll
                for (int i = 0; i < 8; ++i) o[i] += (float)vv[i] * wl[cg + i][tap];
            }
        }
        bf16x8 ov = {(__bf16)o[0], (__bf16)o[1], (__bf16)o[2], (__bf16)o[3],
                     (__bf16)o[4], (__bf16)o[5], (__bf16)o[6], (__bf16)o[7]};
        *(bf16x8*)&at[px][cg] = ov;
    }
    __syncthreads();

    // ---- phase 2: proj. wave w -> outputs [w*32, w*32+32), px = col ----
    const int w = tid >> 6, lane = tid & 63;
    const int col = lane & 15, g = lane >> 4;
    const int obase = w * 32;

    #pragma unroll
    for (int ot = 0; ot < 2; ++ot) {
        const float* wrow = proj_w + (size_t)(obase + ot * 16 + col) * CCH;
        f32x4 acc = {0.f, 0.f, 0.f, 0.f};
        #pragma unroll
        for (int ks = 0; ks < 4; ++ks) {
            const int c0 = ks * 32 + g * 8;
            const float4 wA = *(const float4*)(wrow + c0);
            const float4 wB = *(const float4*)(wrow + c0 + 4);
            bf16x8 af = {(__bf16)wA.x, (__bf16)wA.y, (__bf16)wA.z, (__bf16)wA.w,
                         (__bf16)wB.x, (__bf16)wB.y, (__bf16)wB.z, (__bf16)wB.w};
            const bf16x8 bf_ = *(const bf16x8*)&at[col][c0];   // one b128
            acc = __builtin_amdgcn_mfma_f32_16x16x32_bf16(af, bf_, acc, 0, 0, 0);
        }
        const f32x4 pb4 = *(const f32x4*)(proj_b + obase + ot * 16 + g * 4);
        #pragma unroll
        for (int r = 0; r < 4; ++r)
            out[(size_t)(b * CCH + obase + ot * 16 + g * 4 + r) * NPIX + px0 + col] =
                acc[r] + pb4[r];
    }
}

// ---------------------------------------------------------------------------
extern "C" void kernel_launch(void* const* d_in, const int* in_sizes, int n_in,
                              void* d_out, int out_size, void* d_ws, size_t ws_size,
                              hipStream_t stream)
{
    const float* x      = (const float*)d_in[0];
    const float* qkv_w  = (const float*)d_in[1];
    const float* qkv_b  = (const float*)d_in[2];
    const float* lepe_w = (const float*)d_in[3];
    const float* lepe_b = (const float*)d_in[4];
    const float* proj_w = (const float*)d_in[5];
    const float* proj_b = (const float*)d_in[6];
    float* out = (float*)d_out;

    char* p = (char*)d_ws;                                   // ~20 MB total
    __bf16* qT = (__bf16*)p;  p += (size_t)2 * NH * NPIX * HD * 2;       // 1.6 MB
    __bf16* kT = (__bf16*)p;  p += (size_t)2 * NH * NPIX * HD * 2;       // 1.6 MB
    __bf16* vT = (__bf16*)p;  p += (size_t)2 * NPIX * CCH * 2;           // 1.6 MB
    __bf16* vP = (__bf16*)p;  p += (size_t)2 * CCH * NPIX * 2;           // 1.6 MB
    __bf16* pO = (__bf16*)p;  p += (size_t)392 * NSPLIT * 64 * 32 * 2;   // 12.8 MB
    float*  pl = (float*)p;                                              // 0.8 MB

    k_qkv  <<<dim3(98, 3, 2), dim3(256), 0, stream>>>(x, qkv_w, qkv_b, qT, kT, vT, vP);
    k_attn <<<dim3(13, 8, 8), dim3(256), 0, stream>>>(qT, kT, vP, pO, pl);
    k_rproj<<<dim3(196, 2),   dim3(256), 0, stream>>>(pO, pl, vT, lepe_w, lepe_b,
                                                      proj_w, proj_b, out);
}